// Round 7
// baseline (206.319 us; speedup 1.0000x reference)
//
#include <hip/hip_runtime.h>
#include <stdint.h>

#define B_SZ 1024
#define NO   16
#define CI   256
#define CO   256
#define BK   64
#define BM   32      // b-rows per block
#define LDA  72      // padded LDS row (shorts): 144B stride, b128 conflict-uniform
#define MAXG 12      // max groups per M (L=3: 11)
#define MAXE 48      // max entries per M (L=3: 39)
#define WP   76      // wconv LDS pad (shorts)

typedef unsigned short u16;
typedef __attribute__((ext_vector_type(8))) short short8;
typedef __attribute__((ext_vector_type(4))) float f32x4;
typedef __attribute__((ext_vector_type(4))) unsigned short u16x4;
typedef __attribute__((ext_vector_type(8))) unsigned short u16x8;

__device__ __forceinline__ u16 f2bf(float f) {
  union { float f; uint32_t u; } v; v.f = f;
  uint32_t u = v.u;
  return (u16)((u + 0x7FFFu + ((u >> 16) & 1u)) >> 16);   // RNE, finite inputs
}
__device__ __forceinline__ float bf2f(u16 h) {
  union { float f; uint32_t u; } v; v.u = ((uint32_t)h) << 16; return v.f;
}

__device__ __forceinline__ f32x4 mfma_16x16x32_bf16(short8 a, short8 b, f32x4 c) {
  asm volatile("v_mfma_f32_16x16x32_bf16 %0, %1, %2, %0" : "+v"(c) : "v"(a), "v"(b));
  return c;
}

// xbf = bf16(x), flat copy-convert, 8 elems/thread
extern "C" __global__ void xconv_kernel(const float* __restrict__ x,
                                        u16* __restrict__ xbf, int n8) {
  int t = blockIdx.x * 256 + threadIdx.x;
  if (t >= n8) return;
  const float* s = x + (size_t)t * 8;
  float4 a = ((const float4*)s)[0];
  float4 b = ((const float4*)s)[1];
  u16x8 pk;
  pk[0] = f2bf(a.x); pk[1] = f2bf(a.y); pk[2] = f2bf(a.z); pk[3] = f2bf(a.w);
  pk[4] = f2bf(b.x); pk[5] = f2bf(b.y); pk[6] = f2bf(b.z); pk[7] = f2bf(b.w);
  *(u16x8*)(xbf + (size_t)t * 8) = pk;
}

// wbf[w][o][i] = bf16(weight[w][i][o]) via 64x64 LDS-transpose tiles (both sides coalesced)
extern "C" __global__ void wconv_kernel(const float* __restrict__ w,
                                        u16* __restrict__ wbf) {
  __shared__ u16 t_lds[64 * WP];
  const int tid = threadIdx.x;
  const int bid = blockIdx.x;
  const int wi = bid >> 4;
  const int i0 = ((bid >> 2) & 3) * 64;
  const int o0 = (bid & 3) * 64;
  const float* src = w + (size_t)wi * (CI * CO);
  u16* dst = wbf + (size_t)wi * (CI * CO);
#pragma unroll
  for (int p = 0; p < 4; ++p) {
    int idx = p * 256 + tid;
    int i = idx >> 4, oq = (idx & 15) * 4;
    float4 v = *(const float4*)(src + (size_t)(i0 + i) * CO + o0 + oq);
    t_lds[(oq + 0) * WP + i] = f2bf(v.x);
    t_lds[(oq + 1) * WP + i] = f2bf(v.y);
    t_lds[(oq + 2) * WP + i] = f2bf(v.z);
    t_lds[(oq + 3) * WP + i] = f2bf(v.w);
  }
  __syncthreads();
#pragma unroll
  for (int p = 0; p < 4; ++p) {
    int idx = p * 256 + tid;
    int o = idx >> 4, iq = (idx & 15) * 4;
    u16x4 v;
    v[0] = t_lds[o * WP + iq + 0]; v[1] = t_lds[o * WP + iq + 1];
    v[2] = t_lds[o * WP + iq + 2]; v[3] = t_lds[o * WP + iq + 3];
    *(u16x4*)(dst + (size_t)(o0 + o) * CI + i0 + iq) = v;
  }
}

extern "C" __global__ void __launch_bounds__(256, 4)
so3_main(const u16* __restrict__ xbf,
         const float* __restrict__ sh,
         const float* __restrict__ CG,
         const u16* __restrict__ wbf,
         const int* __restrict__ M1,
         const int* __restrict__ M2,
         const int* __restrict__ seg1,
         const int* __restrict__ lind,
         const int* __restrict__ seg2,
         float* __restrict__ out,
         int G, int nnz) {
  __shared__ u16 As[2][BM * LDA];           // 9.2 KB double-buffered A tile
  __shared__ float coefs[MAXE][BM];         // 6.1 KB
  __shared__ int s_meta[4];
  __shared__ int s_estart[MAXG], s_eend[MAXG], s_wind[MAXG], s_m1[MAXE];

  const int tid = threadIdx.x;
  const int bid = blockIdx.x;
  const int b0  = (bid & 31) * BM;          // XCD = bid%8 -> x slab L2-resident
  const int M   = (bid >> 5) & 15;
  const int co0 = (bid >> 9) * 128;

  if (tid == 0) { s_meta[0] = 1 << 30; s_meta[1] = 0; s_meta[2] = 1 << 30; s_meta[3] = 0; }
  if (tid < MAXG) { s_estart[tid] = 1 << 30; s_eend[tid] = 0; }
  __syncthreads();
  for (int g = tid; g < G; g += 256)
    if (seg2[g] == M) { atomicMin(&s_meta[0], g); atomicMax(&s_meta[1], g + 1); }
  __syncthreads();
  const int gstart = s_meta[0];
  const int ng = s_meta[1] - gstart;        // groups for this M are contiguous
  for (int e = tid; e < nnz; e += 256) {
    int g = seg1[e] - gstart;
    if (g >= 0 && g < ng) {
      atomicMin(&s_meta[2], e); atomicMax(&s_meta[3], e + 1);
      atomicMin(&s_estart[g], e); atomicMax(&s_eend[g], e + 1);
    }
  }
  __syncthreads();
  const int e0 = s_meta[2];
  const int ne = s_meta[3] - e0;            // <= 39 for L=3
  for (int i = tid; i < ng; i += 256) s_wind[i] = lind[gstart + i];
  for (int i = tid; i < ne; i += 256) s_m1[i] = M1[e0 + i];
  for (int idx = tid; idx < ne * BM; idx += 256) {
    int el = idx / BM, r = idx & (BM - 1);
    int e = e0 + el;
    coefs[el][r] = CG[e] * sh[(size_t)(b0 + r) * NO + M2[e]];
  }
  __syncthreads();

  const int lane = tid & 63;
  const int wn = tid >> 6;                  // 4 waves: 32-col strips of BN=128
  const int lrow = lane & 15, lq = lane >> 4;
  const int ar = tid >> 3;                  // A-build: row 0..31
  const int ak = (tid & 7) * 8;             // A-build: k-octet (shorts)

  f32x4 acc[2][2];
#pragma unroll
  for (int i = 0; i < 2; ++i)
#pragma unroll
    for (int j = 0; j < 2; ++j) acc[i][j] = (f32x4){0.f, 0.f, 0.f, 0.f};

  const int T = ng * 4;

  // B-fragments direct global->reg: per wave frag (nf,ks), lane reads 16B at
  // row (nf*16+lrow), k-bytes (ks*64 + lq*16): 4 lanes/row cover one 64B line.
  auto loadB = [&](int tt, short8* dst) {
    int gl = tt >> 2, kk = (tt & 3) * BK;
    const u16* wb = wbf + (size_t)s_wind[gl] * (CI * CO)
                  + (size_t)(co0 + wn * 32) * CI + kk;
#pragma unroll
    for (int nf = 0; nf < 2; ++nf)
#pragma unroll
      for (int ks = 0; ks < 2; ++ks)
        dst[nf * 2 + ks] =
            *(const short8*)(wb + (size_t)(nf * 16 + lrow) * CI + ks * 32 + lq * 8);
  };

  auto buildA = [&](int tt) {
    int gl = tt >> 2, kk = (tt & 3) * BK;
    int ea = s_estart[gl] - e0, eb = s_eend[gl] - e0;
    const u16* xrow = xbf + (size_t)(b0 + ar) * (NO * CI) + kk + ak;
    float ax[8];
#pragma unroll
    for (int j = 0; j < 8; ++j) ax[j] = 0.f;
    for (int el = ea; el < eb; ++el) {
      float cf = coefs[el][ar];
      u16x8 xv = *(const u16x8*)(xrow + (size_t)s_m1[el] * CI);
#pragma unroll
      for (int j = 0; j < 8; ++j) ax[j] = fmaf(cf, bf2f(xv[j]), ax[j]);
    }
    uint32_t d0, d1, d2, d3;   // packed RNE bf16 pairs, 1 inst per 2 elems
    asm("v_cvt_pk_bf16_f32 %0, %1, %2" : "=v"(d0) : "v"(ax[0]), "v"(ax[1]));
    asm("v_cvt_pk_bf16_f32 %0, %1, %2" : "=v"(d1) : "v"(ax[2]), "v"(ax[3]));
    asm("v_cvt_pk_bf16_f32 %0, %1, %2" : "=v"(d2) : "v"(ax[4]), "v"(ax[5]));
    asm("v_cvt_pk_bf16_f32 %0, %1, %2" : "=v"(d3) : "v"(ax[6]), "v"(ax[7]));
    union { u16x8 v; uint32_t d[4]; } u;
    u.d[0] = d0; u.d[1] = d1; u.d[2] = d2; u.d[3] = d3;
    *(u16x8*)&As[tt & 1][ar * LDA + ak] = u.v;
  };

  auto mmaPhase = [&](int tt, const short8* bc) {
    const u16* Ab = As[tt & 1];
#pragma unroll
    for (int ks = 0; ks < 2; ++ks) {
      short8 af[2];
#pragma unroll
      for (int mf = 0; mf < 2; ++mf)
        af[mf] = *(const short8*)&Ab[(mf * 16 + lrow) * LDA + ks * 32 + lq * 8];
#pragma unroll
      for (int mf = 0; mf < 2; ++mf)
#pragma unroll
        for (int nf = 0; nf < 2; ++nf)
          acc[mf][nf] = mfma_16x16x32_bf16(af[mf], bc[nf * 2 + ks], acc[mf][nf]);
    }
  };

  short8 bA[4], bB[4];
  buildA(0);                                 // -> As[0]
  loadB(0, bA);
  // one barrier per phase: As double-buffer removes read-before-overwrite barrier;
  // B is register-resident (no LDS, no barrier coupling). T = ng*4 is even.
  for (int t = 0; t < T; t += 2) {
    __syncthreads();
    loadB(t + 1, bB);                        // prefetch B(t+1), in flight across MFMA
    mmaPhase(t, bA);
    buildA(t + 1);                           // -> As[(t+1)&1]
    __syncthreads();
    loadB(t + 2 < T ? t + 2 : t + 1, bA);
    mmaPhase(t + 1, bB);
    if (t + 2 < T) buildA(t + 2);
  }

  // ---- epilogue: C layout col=lane&15, row=(lane>>4)*4+reg ----
#pragma unroll
  for (int mf = 0; mf < 2; ++mf) {
    int brow = b0 + mf * 16 + lq * 4;
#pragma unroll
    for (int nf = 0; nf < 2; ++nf) {
      int o = co0 + wn * 32 + nf * 16 + lrow;
#pragma unroll
      for (int rg = 0; rg < 4; ++rg)
        out[(size_t)(brow + rg) * (NO * CO) + (size_t)M * CO + o] = acc[mf][nf][rg];
    }
  }
}

extern "C" void kernel_launch(void* const* d_in, const int* in_sizes, int n_in,
                              void* d_out, int out_size, void* d_ws, size_t ws_size,
                              hipStream_t stream) {
  const float* x   = (const float*)d_in[0];
  const float* sh  = (const float*)d_in[1];
  const float* wgt = (const float*)d_in[2];
  const float* CG  = (const float*)d_in[3];
  const int* M1    = (const int*)d_in[4];
  const int* M2    = (const int*)d_in[5];
  const int* seg1  = (const int*)d_in[6];
  const int* lind  = (const int*)d_in[7];
  const int* seg2  = (const int*)d_in[8];
  float* out       = (float*)d_out;

  const int nnz = in_sizes[3];
  const int G   = in_sizes[7];
  const int n_w = in_sizes[2] / (CI * CO);

  u16* xbf = (u16*)d_ws;                                        // 8.39 MB
  u16* wbf = (u16*)((char*)d_ws + (size_t)B_SZ * NO * CI * 2);  // 4.46 MB

  int n8 = B_SZ * NO * CI / 8;
  xconv_kernel<<<dim3(n8 / 256), dim3(256), 0, stream>>>(x, xbf, n8);
  wconv_kernel<<<dim3(n_w * 16), dim3(256), 0, stream>>>(wgt, wbf);
  so3_main<<<dim3(1024), dim3(256), 0, stream>>>(xbf, sh, CG, wbf, M1, M2, seg1, lind, seg2,
                                                 out, G, nnz);
}

// Round 8
// 175.162 us; speedup vs baseline: 1.1779x; 1.1779x over previous
//
#include <hip/hip_runtime.h>
#include <stdint.h>

#define B_SZ 1024
#define NO   16
#define CI   256
#define CO   256
#define BK   64
#define BM   32      // b-rows per block
#define LDB  72      // Bs padded row (shorts): 144B stride
#define LDAA 264     // As padded row (shorts): 528B stride, full CI=256 + 8 pad
#define MAXG 12      // max groups per M (L=3: 11)
#define MAXE 48      // max entries per M (L=3: 39)
#define WP   76      // wconv LDS pad (shorts)

typedef unsigned short u16;
typedef __attribute__((ext_vector_type(8))) short short8;
typedef __attribute__((ext_vector_type(4))) float f32x4;
typedef __attribute__((ext_vector_type(4))) unsigned short u16x4;
typedef __attribute__((ext_vector_type(8))) unsigned short u16x8;

__device__ __forceinline__ u16 f2bf(float f) {
  union { float f; uint32_t u; } v; v.f = f;
  uint32_t u = v.u;
  return (u16)((u + 0x7FFFu + ((u >> 16) & 1u)) >> 16);   // RNE, finite inputs
}
__device__ __forceinline__ float bf2f(u16 h) {
  union { float f; uint32_t u; } v; v.u = ((uint32_t)h) << 16; return v.f;
}

__device__ __forceinline__ f32x4 mfma_16x16x32_bf16(short8 a, short8 b, f32x4 c) {
  asm volatile("v_mfma_f32_16x16x32_bf16 %0, %1, %2, %0" : "+v"(c) : "v"(a), "v"(b));
  return c;
}

// xbf = bf16(x), flat copy-convert, 8 elems/thread
extern "C" __global__ void xconv_kernel(const float* __restrict__ x,
                                        u16* __restrict__ xbf, int n8) {
  int t = blockIdx.x * 256 + threadIdx.x;
  if (t >= n8) return;
  const float* s = x + (size_t)t * 8;
  float4 a = ((const float4*)s)[0];
  float4 b = ((const float4*)s)[1];
  u16x8 pk;
  pk[0] = f2bf(a.x); pk[1] = f2bf(a.y); pk[2] = f2bf(a.z); pk[3] = f2bf(a.w);
  pk[4] = f2bf(b.x); pk[5] = f2bf(b.y); pk[6] = f2bf(b.z); pk[7] = f2bf(b.w);
  *(u16x8*)(xbf + (size_t)t * 8) = pk;
}

// wbf[w][o][i] = bf16(weight[w][i][o]) via 64x64 LDS-transpose tiles
extern "C" __global__ void wconv_kernel(const float* __restrict__ w,
                                        u16* __restrict__ wbf) {
  __shared__ u16 t_lds[64 * WP];
  const int tid = threadIdx.x;
  const int bid = blockIdx.x;
  const int wi = bid >> 4;
  const int i0 = ((bid >> 2) & 3) * 64;
  const int o0 = (bid & 3) * 64;
  const float* src = w + (size_t)wi * (CI * CO);
  u16* dst = wbf + (size_t)wi * (CI * CO);
#pragma unroll
  for (int p = 0; p < 4; ++p) {
    int idx = p * 256 + tid;
    int i = idx >> 4, oq = (idx & 15) * 4;
    float4 v = *(const float4*)(src + (size_t)(i0 + i) * CO + o0 + oq);
    t_lds[(oq + 0) * WP + i] = f2bf(v.x);
    t_lds[(oq + 1) * WP + i] = f2bf(v.y);
    t_lds[(oq + 2) * WP + i] = f2bf(v.z);
    t_lds[(oq + 3) * WP + i] = f2bf(v.w);
  }
  __syncthreads();
#pragma unroll
  for (int p = 0; p < 4; ++p) {
    int idx = p * 256 + tid;
    int o = idx >> 4, iq = (idx & 15) * 4;
    u16x4 v;
    v[0] = t_lds[o * WP + iq + 0]; v[1] = t_lds[o * WP + iq + 1];
    v[2] = t_lds[o * WP + iq + 2]; v[3] = t_lds[o * WP + iq + 3];
    *(u16x4*)(dst + (size_t)(o0 + o) * CI + i0 + iq) = v;
  }
}

extern "C" __global__ void __launch_bounds__(256, 4)
so3_main(const u16* __restrict__ xbf,
         const float* __restrict__ sh,
         const float* __restrict__ CG,
         const u16* __restrict__ wbf,
         const int* __restrict__ M1,
         const int* __restrict__ M2,
         const int* __restrict__ seg1,
         const int* __restrict__ lind,
         const int* __restrict__ seg2,
         float* __restrict__ out,
         int G, int nnz) {
  __shared__ u16 As[BM * LDAA];             // 16.9 KB: full-CI A tile (single buffer)
  __shared__ u16 Bs[128 * LDB];             // 18.4 KB
  __shared__ u16 coefs[MAXE][BM];           // 3 KB (bf16)
  __shared__ int s_meta[4];
  __shared__ int s_estart[MAXG], s_eend[MAXG], s_wind[MAXG], s_m1[MAXE];

  const int tid = threadIdx.x;
  const int bid = blockIdx.x;
  const int b0  = (bid & 31) * BM;          // XCD = bid%8 -> x slab L2-resident
  const int M   = (bid >> 5) & 15;
  const int co0 = (bid >> 9) * 128;

  if (tid == 0) { s_meta[0] = 1 << 30; s_meta[1] = 0; s_meta[2] = 1 << 30; s_meta[3] = 0; }
  if (tid < MAXG) { s_estart[tid] = 1 << 30; s_eend[tid] = 0; }
  if (tid < MAXE) s_m1[tid] = 0;
  __syncthreads();
  for (int g = tid; g < G; g += 256)
    if (seg2[g] == M) { atomicMin(&s_meta[0], g); atomicMax(&s_meta[1], g + 1); }
  __syncthreads();
  const int gstart = s_meta[0];
  const int ng = s_meta[1] - gstart;        // groups for this M are contiguous
  for (int e = tid; e < nnz; e += 256) {
    int g = seg1[e] - gstart;
    if (g >= 0 && g < ng) {
      atomicMin(&s_meta[2], e); atomicMax(&s_meta[3], e + 1);
      atomicMin(&s_estart[g], e); atomicMax(&s_eend[g], e + 1);
    }
  }
  __syncthreads();
  const int e0 = s_meta[2];
  const int ne = s_meta[3] - e0;            // <= 39 for L=3
  for (int i = tid; i < ng; i += 256) s_wind[i] = lind[gstart + i];
  for (int i = tid; i < ne; i += 256) s_m1[i] = M1[e0 + i];
  for (int idx = tid; idx < ne * BM; idx += 256) {
    int el = idx / BM, r = idx & (BM - 1);
    int e = e0 + el;
    coefs[el][r] = f2bf(CG[e] * sh[(size_t)(b0 + r) * NO + M2[e]]);
  }
  __syncthreads();

  const int lane = tid & 63;
  const int wn = tid >> 6;                  // 4 waves: 32-col strips of BN=128
  const int lrow = lane & 15, lq = lane >> 4;
  const int ar = tid >> 3;                  // A-build: row 0..31
  const int ak = (tid & 7) * 8;             // A-build: k-octet (shorts)

  f32x4 acc[2][2];
#pragma unroll
  for (int i = 0; i < 2; ++i)
#pragma unroll
    for (int j = 0; j < 2; ++j) acc[i][j] = (f32x4){0.f, 0.f, 0.f, 0.f};

  const int T = ng * 4;

  // full-CI A build, once per group: entry metadata hoisted to regs (one LDS
  // burst), entry pairs with 8 independent x-loads in flight (latency ILP).
  auto buildA = [&](int gl) {
    const int ea = s_estart[gl] - e0;
    const int cnt = (s_eend[gl] - e0) - ea;
    const u16* xb = xbf + (size_t)(b0 + ar) * (NO * CI) + ak;
    float cf[8]; int mo[8];
    const int mo0 = s_m1[ea] * CI;
#pragma unroll
    for (int j = 0; j < 8; ++j) {
      bool v = j < cnt;                      // ea+j stays in-bounds of MAXE arrays
      cf[j] = v ? bf2f(coefs[ea + j][ar]) : 0.f;
      mo[j] = v ? s_m1[ea + j] * CI : mo0;
    }
    float ax[4][8];
#pragma unroll
    for (int q = 0; q < 4; ++q)
#pragma unroll
      for (int j = 0; j < 8; ++j) ax[q][j] = 0.f;
#pragma unroll
    for (int p = 0; p < 4; ++p) {            // entry pairs; cnt is block-uniform
      if (2 * p < cnt) {
        u16x8 vX[4], vY[4];
#pragma unroll
        for (int q = 0; q < 4; ++q) vX[q] = *(const u16x8*)(xb + mo[2 * p] + q * 64);
#pragma unroll
        for (int q = 0; q < 4; ++q) vY[q] = *(const u16x8*)(xb + mo[2 * p + 1] + q * 64);
        const float c0 = cf[2 * p], c1 = cf[2 * p + 1];
#pragma unroll
        for (int q = 0; q < 4; ++q)
#pragma unroll
          for (int j = 0; j < 8; ++j)
            ax[q][j] = fmaf(c1, bf2f((u16)vY[q][j]),
                       fmaf(c0, bf2f((u16)vX[q][j]), ax[q][j]));
      }
    }
#pragma unroll
    for (int q = 0; q < 4; ++q) {
      u16x8 pk;
#pragma unroll
      for (int j = 0; j < 8; ++j) pk[j] = f2bf(ax[q][j]);
      *(u16x8*)&As[ar * LDAA + q * 64 + ak] = pk;
    }
  };

  u16x8 breg[4];
  {   // prefetch B(0)
    const u16* wb = wbf + (size_t)s_wind[0] * (CI * CO) + (size_t)co0 * CI;
#pragma unroll
    for (int rr = 0; rr < 4; ++rr) {
      int idx = tid + rr * 256, o = idx >> 3, ic = (idx & 7) * 8;
      breg[rr] = *(const u16x8*)(wb + (size_t)o * CI + ic);
    }
  }

  for (int t = 0; t < T; ++t) {
    const int gl = t >> 2, kk = t & 3;
    if (kk == 0) buildA(gl);                 // prev group's MFMA ended with barrier
    // ---- B: write prefetched regs (phase t) to LDS ----
#pragma unroll
    for (int rr = 0; rr < 4; ++rr) {
      int idx = tid + rr * 256, o = idx >> 3, ic = (idx & 7) * 8;
      *(u16x8*)&Bs[o * LDB + ic] = breg[rr];
    }
    // ---- issue next-phase B loads ----
    {
      int tn = (t + 1 < T) ? t + 1 : t;
      int gln = tn >> 2, kkn = (tn & 3) * BK;
      const u16* wbn = wbf + (size_t)s_wind[gln] * (CI * CO) + (size_t)co0 * CI + kkn;
#pragma unroll
      for (int rr = 0; rr < 4; ++rr) {
        int idx = tid + rr * 256, o = idx >> 3, ic = (idx & 7) * 8;
        breg[rr] = *(const u16x8*)(wbn + (size_t)o * CI + ic);
      }
    }
    __syncthreads();
    // ---- MFMA: 2 k-substeps x 2x2 fragments per wave ----
#pragma unroll
    for (int ks = 0; ks < 2; ++ks) {
      short8 af[2], bfr[2];
#pragma unroll
      for (int mf = 0; mf < 2; ++mf)
        af[mf] = *(const short8*)&As[(mf * 16 + lrow) * LDAA + kk * 64 + ks * 32 + lq * 8];
#pragma unroll
      for (int nf = 0; nf < 2; ++nf)
        bfr[nf] = *(const short8*)&Bs[(wn * 32 + nf * 16 + lrow) * LDB + ks * 32 + lq * 8];
#pragma unroll
      for (int mf = 0; mf < 2; ++mf)
#pragma unroll
        for (int nf = 0; nf < 2; ++nf)
          acc[mf][nf] = mfma_16x16x32_bf16(af[mf], bfr[nf], acc[mf][nf]);
    }
    __syncthreads();
  }

  // ---- epilogue: C layout col=lane&15, row=(lane>>4)*4+reg ----
#pragma unroll
  for (int mf = 0; mf < 2; ++mf) {
    int brow = b0 + mf * 16 + lq * 4;
#pragma unroll
    for (int nf = 0; nf < 2; ++nf) {
      int o = co0 + wn * 32 + nf * 16 + lrow;
#pragma unroll
      for (int rg = 0; rg < 4; ++rg)
        out[(size_t)(brow + rg) * (NO * CO) + (size_t)M * CO + o] = acc[mf][nf][rg];
    }
  }
}

extern "C" void kernel_launch(void* const* d_in, const int* in_sizes, int n_in,
                              void* d_out, int out_size, void* d_ws, size_t ws_size,
                              hipStream_t stream) {
  const float* x   = (const float*)d_in[0];
  const float* sh  = (const float*)d_in[1];
  const float* wgt = (const float*)d_in[2];
  const float* CG  = (const float*)d_in[3];
  const int* M1    = (const int*)d_in[4];
  const int* M2    = (const int*)d_in[5];
  const int* seg1  = (const int*)d_in[6];
  const int* lind  = (const int*)d_in[7];
  const int* seg2  = (const int*)d_in[8];
  float* out       = (float*)d_out;

  const int nnz = in_sizes[3];
  const int G   = in_sizes[7];
  const int n_w = in_sizes[2] / (CI * CO);

  u16* xbf = (u16*)d_ws;                                        // 8.39 MB
  u16* wbf = (u16*)((char*)d_ws + (size_t)B_SZ * NO * CI * 2);  // 4.46 MB

  int n8 = B_SZ * NO * CI / 8;
  xconv_kernel<<<dim3(n8 / 256), dim3(256), 0, stream>>>(x, xbf, n8);
  wconv_kernel<<<dim3(n_w * 16), dim3(256), 0, stream>>>(wgt, wbf);
  so3_main<<<dim3(1024), dim3(256), 0, stream>>>(xbf, sh, CG, wbf, M1, M2, seg1, lind, seg2,
                                                 out, G, nnz);
}

// Round 9
// 162.161 us; speedup vs baseline: 1.2723x; 1.0802x over previous
//
#include <hip/hip_runtime.h>
#include <stdint.h>

#define B_SZ 1024
#define NO   16
#define CI   256
#define CO   256
#define BK   64
#define BM   32      // b-rows per block
#define LDB  72      // Bs padded row (shorts): 144B stride
#define LDAA 264     // As padded row (shorts): 528B stride, full CI=256 + 8 pad
#define MAXG 12      // max groups per M (L=3: 11)
#define MAXE 48      // max entries per M (L=3: 39)
#define WP   76      // wconv LDS pad (shorts)

typedef unsigned short u16;
typedef __attribute__((ext_vector_type(8))) short short8;
typedef __attribute__((ext_vector_type(4))) float f32x4;
typedef __attribute__((ext_vector_type(4))) unsigned short u16x4;
typedef __attribute__((ext_vector_type(8))) unsigned short u16x8;

__device__ __forceinline__ u16 f2bf(float f) {
  union { float f; uint32_t u; } v; v.f = f;
  uint32_t u = v.u;
  return (u16)((u + 0x7FFFu + ((u >> 16) & 1u)) >> 16);   // RNE, finite inputs
}
__device__ __forceinline__ float bf2f(u16 h) {
  union { float f; uint32_t u; } v; v.u = ((uint32_t)h) << 16; return v.f;
}

__device__ __forceinline__ f32x4 mfma_16x16x32_bf16(short8 a, short8 b, f32x4 c) {
  asm volatile("v_mfma_f32_16x16x32_bf16 %0, %1, %2, %0" : "+v"(c) : "v"(a), "v"(b));
  return c;
}

// xbf = bf16(x), flat copy-convert, 8 elems/thread
extern "C" __global__ void xconv_kernel(const float* __restrict__ x,
                                        u16* __restrict__ xbf, int n8) {
  int t = blockIdx.x * 256 + threadIdx.x;
  if (t >= n8) return;
  const float* s = x + (size_t)t * 8;
  float4 a = ((const float4*)s)[0];
  float4 b = ((const float4*)s)[1];
  u16x8 pk;
  pk[0] = f2bf(a.x); pk[1] = f2bf(a.y); pk[2] = f2bf(a.z); pk[3] = f2bf(a.w);
  pk[4] = f2bf(b.x); pk[5] = f2bf(b.y); pk[6] = f2bf(b.z); pk[7] = f2bf(b.w);
  *(u16x8*)(xbf + (size_t)t * 8) = pk;
}

// wbf[w][o][i] = bf16(weight[w][i][o]) via 64x64 LDS-transpose tiles
extern "C" __global__ void wconv_kernel(const float* __restrict__ w,
                                        u16* __restrict__ wbf) {
  __shared__ u16 t_lds[64 * WP];
  const int tid = threadIdx.x;
  const int bid = blockIdx.x;
  const int wi = bid >> 4;
  const int i0 = ((bid >> 2) & 3) * 64;
  const int o0 = (bid & 3) * 64;
  const float* src = w + (size_t)wi * (CI * CO);
  u16* dst = wbf + (size_t)wi * (CI * CO);
#pragma unroll
  for (int p = 0; p < 4; ++p) {
    int idx = p * 256 + tid;
    int i = idx >> 4, oq = (idx & 15) * 4;
    float4 v = *(const float4*)(src + (size_t)(i0 + i) * CO + o0 + oq);
    t_lds[(oq + 0) * WP + i] = f2bf(v.x);
    t_lds[(oq + 1) * WP + i] = f2bf(v.y);
    t_lds[(oq + 2) * WP + i] = f2bf(v.z);
    t_lds[(oq + 3) * WP + i] = f2bf(v.w);
  }
  __syncthreads();
#pragma unroll
  for (int p = 0; p < 4; ++p) {
    int idx = p * 256 + tid;
    int o = idx >> 4, iq = (idx & 15) * 4;
    u16x4 v;
    v[0] = t_lds[o * WP + iq + 0]; v[1] = t_lds[o * WP + iq + 1];
    v[2] = t_lds[o * WP + iq + 2]; v[3] = t_lds[o * WP + iq + 3];
    *(u16x4*)(dst + (size_t)(o0 + o) * CI + i0 + iq) = v;
  }
}

extern "C" __global__ void __launch_bounds__(256)
__attribute__((amdgpu_waves_per_eu(4, 4)))   // pin 4 waves/EU: VGPR budget 128, no spill incentive
so3_main(const u16* __restrict__ xbf,
         const float* __restrict__ sh,
         const float* __restrict__ CG,
         const u16* __restrict__ wbf,
         const int* __restrict__ M1,
         const int* __restrict__ M2,
         const int* __restrict__ seg1,
         const int* __restrict__ lind,
         const int* __restrict__ seg2,
         float* __restrict__ out,
         int G, int nnz) {
  __shared__ u16 As[BM * LDAA];             // 16.9 KB: full-CI A tile (single buffer)
  __shared__ u16 Bs[128 * LDB];             // 18.4 KB
  __shared__ u16 coefs[MAXE][BM];           // 3 KB (bf16)
  __shared__ int s_meta[4];
  __shared__ int s_estart[MAXG], s_eend[MAXG], s_wind[MAXG], s_m1[MAXE];

  const int tid = threadIdx.x;
  const int bid = blockIdx.x;
  const int b0  = (bid & 31) * BM;          // XCD = bid%8 -> x slab L2-resident
  const int M   = (bid >> 5) & 15;
  const int co0 = (bid >> 9) * 128;

  if (tid == 0) { s_meta[0] = 1 << 30; s_meta[1] = 0; s_meta[2] = 1 << 30; s_meta[3] = 0; }
  if (tid < MAXG) { s_estart[tid] = 1 << 30; s_eend[tid] = 0; }
  if (tid < MAXE) s_m1[tid] = 0;
  __syncthreads();
  for (int g = tid; g < G; g += 256)
    if (seg2[g] == M) { atomicMin(&s_meta[0], g); atomicMax(&s_meta[1], g + 1); }
  __syncthreads();
  const int gstart = s_meta[0];
  const int ng = s_meta[1] - gstart;        // groups for this M are contiguous
  for (int e = tid; e < nnz; e += 256) {
    int g = seg1[e] - gstart;
    if (g >= 0 && g < ng) {
      atomicMin(&s_meta[2], e); atomicMax(&s_meta[3], e + 1);
      atomicMin(&s_estart[g], e); atomicMax(&s_eend[g], e + 1);
    }
  }
  __syncthreads();
  const int e0 = s_meta[2];
  const int ne = s_meta[3] - e0;            // <= 39 for L=3
  for (int i = tid; i < ng; i += 256) s_wind[i] = lind[gstart + i];
  for (int i = tid; i < ne; i += 256) s_m1[i] = M1[e0 + i];
  for (int idx = tid; idx < ne * BM; idx += 256) {
    int el = idx / BM, r = idx & (BM - 1);
    int e = e0 + el;
    coefs[el][r] = f2bf(CG[e] * sh[(size_t)(b0 + r) * NO + M2[e]]);
  }
  __syncthreads();

  const int lane = tid & 63;
  const int wn = tid >> 6;                  // 4 waves: 32-col strips of BN=128
  const int lrow = lane & 15, lq = lane >> 4;
  const int ar = tid >> 3;                  // A-build: row 0..31
  const int ak = (tid & 7) * 8;             // A-build: k-octet (shorts)

  f32x4 acc[2][2];
#pragma unroll
  for (int i = 0; i < 2; ++i)
#pragma unroll
    for (int j = 0; j < 2; ++j) acc[i][j] = (f32x4){0.f, 0.f, 0.f, 0.f};

  const int T = ng * 4;

  // full-CI A build, once per group, in two 128-col halves (halved live regs
  // vs r8 -> no spill). Per pair-half: 4 independent 16B x-loads in flight.
  auto buildA = [&](int gl) {
    const int ea = s_estart[gl] - e0;
    const int cnt = (s_eend[gl] - e0) - ea;
    const u16* xb = xbf + (size_t)(b0 + ar) * (NO * CI) + ak;
    float cf[8]; int mo[8];
    const int mo0 = s_m1[ea] * CI;
#pragma unroll
    for (int j = 0; j < 8; ++j) {
      bool v = j < cnt;                      // ea+j stays in-bounds of MAXE arrays
      cf[j] = v ? bf2f(coefs[ea + j][ar]) : 0.f;
      mo[j] = v ? s_m1[ea + j] * CI : mo0;
    }
#pragma unroll
    for (int h = 0; h < 2; ++h) {
      float ax[2][8];
#pragma unroll
      for (int q = 0; q < 2; ++q)
#pragma unroll
        for (int j = 0; j < 8; ++j) ax[q][j] = 0.f;
#pragma unroll
      for (int p = 0; p < 4; ++p) {          // entry pairs; cnt is block-uniform
        if (2 * p < cnt) {
          u16x8 vX[2], vY[2];
#pragma unroll
          for (int q = 0; q < 2; ++q) vX[q] = *(const u16x8*)(xb + mo[2 * p] + (2 * h + q) * 64);
#pragma unroll
          for (int q = 0; q < 2; ++q) vY[q] = *(const u16x8*)(xb + mo[2 * p + 1] + (2 * h + q) * 64);
          const float c0 = cf[2 * p], c1 = cf[2 * p + 1];
#pragma unroll
          for (int q = 0; q < 2; ++q)
#pragma unroll
            for (int j = 0; j < 8; ++j)
              ax[q][j] = fmaf(c1, bf2f((u16)vY[q][j]),
                         fmaf(c0, bf2f((u16)vX[q][j]), ax[q][j]));
        }
      }
#pragma unroll
      for (int q = 0; q < 2; ++q) {
        u16x8 pk;
#pragma unroll
        for (int j = 0; j < 8; ++j) pk[j] = f2bf(ax[q][j]);
        *(u16x8*)&As[ar * LDAA + (2 * h + q) * 64 + ak] = pk;
      }
    }
  };

  u16x8 breg[4];
  {   // prefetch B(0)
    const u16* wb = wbf + (size_t)s_wind[0] * (CI * CO) + (size_t)co0 * CI;
#pragma unroll
    for (int rr = 0; rr < 4; ++rr) {
      int idx = tid + rr * 256, o = idx >> 3, ic = (idx & 7) * 8;
      breg[rr] = *(const u16x8*)(wb + (size_t)o * CI + ic);
    }
  }

  for (int t = 0; t < T; ++t) {
    const int gl = t >> 2, kk = t & 3;
    if (kk == 0) buildA(gl);                 // prev group's MFMA ended with barrier
    // ---- B: write prefetched regs (phase t) to LDS ----
#pragma unroll
    for (int rr = 0; rr < 4; ++rr) {
      int idx = tid + rr * 256, o = idx >> 3, ic = (idx & 7) * 8;
      *(u16x8*)&Bs[o * LDB + ic] = breg[rr];
    }
    // ---- issue next-phase B loads ----
    {
      int tn = (t + 1 < T) ? t + 1 : t;
      int gln = tn >> 2, kkn = (tn & 3) * BK;
      const u16* wbn = wbf + (size_t)s_wind[gln] * (CI * CO) + (size_t)co0 * CI + kkn;
#pragma unroll
      for (int rr = 0; rr < 4; ++rr) {
        int idx = tid + rr * 256, o = idx >> 3, ic = (idx & 7) * 8;
        breg[rr] = *(const u16x8*)(wbn + (size_t)o * CI + ic);
      }
    }
    __syncthreads();
    // ---- MFMA: 2 k-substeps x 2x2 fragments per wave ----
#pragma unroll
    for (int ks = 0; ks < 2; ++ks) {
      short8 af[2], bfr[2];
#pragma unroll
      for (int mf = 0; mf < 2; ++mf)
        af[mf] = *(const short8*)&As[(mf * 16 + lrow) * LDAA + kk * 64 + ks * 32 + lq * 8];
#pragma unroll
      for (int nf = 0; nf < 2; ++nf)
        bfr[nf] = *(const short8*)&Bs[(wn * 32 + nf * 16 + lrow) * LDB + ks * 32 + lq * 8];
#pragma unroll
      for (int mf = 0; mf < 2; ++mf)
#pragma unroll
        for (int nf = 0; nf < 2; ++nf)
          acc[mf][nf] = mfma_16x16x32_bf16(af[mf], bfr[nf], acc[mf][nf]);
    }
    __syncthreads();
  }

  // ---- epilogue: C layout col=lane&15, row=(lane>>4)*4+reg ----
#pragma unroll
  for (int mf = 0; mf < 2; ++mf) {
    int brow = b0 + mf * 16 + lq * 4;
#pragma unroll
    for (int nf = 0; nf < 2; ++nf) {
      int o = co0 + wn * 32 + nf * 16 + lrow;
#pragma unroll
      for (int rg = 0; rg < 4; ++rg)
        out[(size_t)(brow + rg) * (NO * CO) + (size_t)M * CO + o] = acc[mf][nf][rg];
    }
  }
}

extern "C" void kernel_launch(void* const* d_in, const int* in_sizes, int n_in,
                              void* d_out, int out_size, void* d_ws, size_t ws_size,
                              hipStream_t stream) {
  const float* x   = (const float*)d_in[0];
  const float* sh  = (const float*)d_in[1];
  const float* wgt = (const float*)d_in[2];
  const float* CG  = (const float*)d_in[3];
  const int* M1    = (const int*)d_in[4];
  const int* M2    = (const int*)d_in[5];
  const int* seg1  = (const int*)d_in[6];
  const int* lind  = (const int*)d_in[7];
  const int* seg2  = (const int*)d_in[8];
  float* out       = (float*)d_out;

  const int nnz = in_sizes[3];
  const int G   = in_sizes[7];
  const int n_w = in_sizes[2] / (CI * CO);

  u16* xbf = (u16*)d_ws;                                        // 8.39 MB
  u16* wbf = (u16*)((char*)d_ws + (size_t)B_SZ * NO * CI * 2);  // 4.46 MB

  int n8 = B_SZ * NO * CI / 8;
  xconv_kernel<<<dim3(n8 / 256), dim3(256), 0, stream>>>(x, xbf, n8);
  wconv_kernel<<<dim3(n_w * 16), dim3(256), 0, stream>>>(wgt, wbf);
  so3_main<<<dim3(1024), dim3(256), 0, stream>>>(xbf, sh, CG, wbf, M1, M2, seg1, lind, seg2,
                                                 out, G, nnz);
}

// Round 10
// 159.003 us; speedup vs baseline: 1.2976x; 1.0199x over previous
//
#include <hip/hip_runtime.h>
#include <stdint.h>

#define B_SZ 1024
#define NO   16
#define CI   256
#define CO   256
#define BK   64
#define BM   32      // b-rows per block
#define LDB  72      // Bs padded row (shorts): 144B stride
#define LDAA 264     // As padded row (shorts): 528B stride, full CI=256 + 8 pad
#define MAXG 12      // max groups per M (L=3: 11)
#define MAXE 48      // max entries per M (L=3: 39)
#define WP   76      // wconv LDS pad (shorts)

typedef unsigned short u16;
typedef __attribute__((ext_vector_type(8))) short short8;
typedef __attribute__((ext_vector_type(4))) float f32x4;
typedef __attribute__((ext_vector_type(4))) unsigned short u16x4;
typedef __attribute__((ext_vector_type(8))) unsigned short u16x8;

__device__ __forceinline__ u16 f2bf(float f) {
  union { float f; uint32_t u; } v; v.f = f;
  uint32_t u = v.u;
  return (u16)((u + 0x7FFFu + ((u >> 16) & 1u)) >> 16);   // RNE, finite inputs
}
__device__ __forceinline__ float bf2f(u16 h) {
  union { float f; uint32_t u; } v; v.u = ((uint32_t)h) << 16; return v.f;
}

__device__ __forceinline__ f32x4 mfma_16x16x32_bf16(short8 a, short8 b, f32x4 c) {
  asm volatile("v_mfma_f32_16x16x32_bf16 %0, %1, %2, %0" : "+v"(c) : "v"(a), "v"(b));
  return c;
}

// xbf = bf16(x), flat copy-convert, 8 elems/thread
extern "C" __global__ void xconv_kernel(const float* __restrict__ x,
                                        u16* __restrict__ xbf, int n8) {
  int t = blockIdx.x * 256 + threadIdx.x;
  if (t >= n8) return;
  const float* s = x + (size_t)t * 8;
  float4 a = ((const float4*)s)[0];
  float4 b = ((const float4*)s)[1];
  u16x8 pk;
  pk[0] = f2bf(a.x); pk[1] = f2bf(a.y); pk[2] = f2bf(a.z); pk[3] = f2bf(a.w);
  pk[4] = f2bf(b.x); pk[5] = f2bf(b.y); pk[6] = f2bf(b.z); pk[7] = f2bf(b.w);
  *(u16x8*)(xbf + (size_t)t * 8) = pk;
}

// wbf[w][o][i] = bf16(weight[w][i][o]) via 64x64 LDS-transpose tiles
extern "C" __global__ void wconv_kernel(const float* __restrict__ w,
                                        u16* __restrict__ wbf) {
  __shared__ u16 t_lds[64 * WP];
  const int tid = threadIdx.x;
  const int bid = blockIdx.x;
  const int wi = bid >> 4;
  const int i0 = ((bid >> 2) & 3) * 64;
  const int o0 = (bid & 3) * 64;
  const float* src = w + (size_t)wi * (CI * CO);
  u16* dst = wbf + (size_t)wi * (CI * CO);
#pragma unroll
  for (int p = 0; p < 4; ++p) {
    int idx = p * 256 + tid;
    int i = idx >> 4, oq = (idx & 15) * 4;
    float4 v = *(const float4*)(src + (size_t)(i0 + i) * CO + o0 + oq);
    t_lds[(oq + 0) * WP + i] = f2bf(v.x);
    t_lds[(oq + 1) * WP + i] = f2bf(v.y);
    t_lds[(oq + 2) * WP + i] = f2bf(v.z);
    t_lds[(oq + 3) * WP + i] = f2bf(v.w);
  }
  __syncthreads();
#pragma unroll
  for (int p = 0; p < 4; ++p) {
    int idx = p * 256 + tid;
    int o = idx >> 4, iq = (idx & 15) * 4;
    u16x4 v;
    v[0] = t_lds[o * WP + iq + 0]; v[1] = t_lds[o * WP + iq + 1];
    v[2] = t_lds[o * WP + iq + 2]; v[3] = t_lds[o * WP + iq + 3];
    *(u16x4*)(dst + (size_t)(o0 + o) * CI + i0 + iq) = v;
  }
}

extern "C" __global__ void __launch_bounds__(256)
__attribute__((amdgpu_waves_per_eu(4, 4)))
so3_main(const u16* __restrict__ xbf,
         const float* __restrict__ sh,
         const float* __restrict__ CG,
         const u16* __restrict__ wbf,
         const int* __restrict__ M1,
         const int* __restrict__ M2,
         const int* __restrict__ seg1,
         const int* __restrict__ lind,
         const int* __restrict__ seg2,
         float* __restrict__ out,
         int G, int nnz) {
  __shared__ u16 As[BM * LDAA];             // 16.9 KB: full-CI A tile, shared by all waves
  __shared__ u16 Bs[128 * LDB];             // 18.4 KB: 4 wave-PRIVATE 32-row strips
  __shared__ u16 coefs[MAXE][BM];           // 3 KB (bf16)
  __shared__ int s_meta[4];
  __shared__ int s_estart[MAXG], s_eend[MAXG], s_wind[MAXG], s_m1[MAXE];

  const int tid = threadIdx.x;
  const int bid = blockIdx.x;
  const int b0  = (bid & 31) * BM;          // XCD = bid%8 -> x slab L2-resident
  const int M   = (bid >> 5) & 15;
  const int co0 = (bid >> 9) * 128;

  if (tid == 0) { s_meta[0] = 1 << 30; s_meta[1] = 0; s_meta[2] = 1 << 30; s_meta[3] = 0; }
  if (tid < MAXG) { s_estart[tid] = 1 << 30; s_eend[tid] = 0; }
  if (tid < MAXE) s_m1[tid] = 0;
  __syncthreads();
  for (int g = tid; g < G; g += 256)
    if (seg2[g] == M) { atomicMin(&s_meta[0], g); atomicMax(&s_meta[1], g + 1); }
  __syncthreads();
  const int gstart = s_meta[0];
  const int ng = s_meta[1] - gstart;        // groups for this M are contiguous
  for (int e = tid; e < nnz; e += 256) {
    int g = seg1[e] - gstart;
    if (g >= 0 && g < ng) {
      atomicMin(&s_meta[2], e); atomicMax(&s_meta[3], e + 1);
      atomicMin(&s_estart[g], e); atomicMax(&s_eend[g], e + 1);
    }
  }
  __syncthreads();
  const int e0 = s_meta[2];
  const int ne = s_meta[3] - e0;            // <= 39 for L=3
  for (int i = tid; i < ng; i += 256) s_wind[i] = lind[gstart + i];
  for (int i = tid; i < ne; i += 256) s_m1[i] = M1[e0 + i];
  for (int idx = tid; idx < ne * BM; idx += 256) {
    int el = idx / BM, r = idx & (BM - 1);
    int e = e0 + el;
    coefs[el][r] = f2bf(CG[e] * sh[(size_t)(b0 + r) * NO + M2[e]]);
  }
  __syncthreads();

  const int lane = tid & 63;
  const int wn = tid >> 6;                  // 4 waves: 32-col strips of BN=128
  const int lrow = lane & 15, lq = lane >> 4;
  const int ar = tid >> 3;                  // A-build: row 0..31
  const int ak = (tid & 7) * 8;             // A-build: k-octet (shorts)
  u16* bsw = &Bs[wn * 32 * LDB];            // this wave's private strip

  f32x4 acc[2][2];
#pragma unroll
  for (int i = 0; i < 2; ++i)
#pragma unroll
    for (int j = 0; j < 2; ++j) acc[i][j] = (f32x4){0.f, 0.f, 0.f, 0.f};

  // full-CI A build, once per group, in two 128-col halves (no spill @64 VGPR)
  auto buildA = [&](int gl) {
    const int ea = s_estart[gl] - e0;
    const int cnt = (s_eend[gl] - e0) - ea;
    const u16* xb = xbf + (size_t)(b0 + ar) * (NO * CI) + ak;
    float cf[8]; int mo[8];
    const int mo0 = s_m1[ea] * CI;
#pragma unroll
    for (int j = 0; j < 8; ++j) {
      bool v = j < cnt;                      // ea+j stays in-bounds of MAXE arrays
      cf[j] = v ? bf2f(coefs[ea + j][ar]) : 0.f;
      mo[j] = v ? s_m1[ea + j] * CI : mo0;
    }
#pragma unroll
    for (int h = 0; h < 2; ++h) {
      float ax[2][8];
#pragma unroll
      for (int q = 0; q < 2; ++q)
#pragma unroll
        for (int j = 0; j < 8; ++j) ax[q][j] = 0.f;
#pragma unroll
      for (int p = 0; p < 4; ++p) {          // entry pairs; cnt is block-uniform
        if (2 * p < cnt) {
          u16x8 vX[2], vY[2];
#pragma unroll
          for (int q = 0; q < 2; ++q) vX[q] = *(const u16x8*)(xb + mo[2 * p] + (2 * h + q) * 64);
#pragma unroll
          for (int q = 0; q < 2; ++q) vY[q] = *(const u16x8*)(xb + mo[2 * p + 1] + (2 * h + q) * 64);
          const float c0 = cf[2 * p], c1 = cf[2 * p + 1];
#pragma unroll
          for (int q = 0; q < 2; ++q)
#pragma unroll
            for (int j = 0; j < 8; ++j)
              ax[q][j] = fmaf(c1, bf2f((u16)vY[q][j]),
                         fmaf(c0, bf2f((u16)vX[q][j]), ax[q][j]));
        }
      }
#pragma unroll
      for (int q = 0; q < 2; ++q) {
        u16x8 pk;
#pragma unroll
        for (int j = 0; j < 8; ++j) pk[j] = f2bf(ax[q][j]);
        *(u16x8*)&As[ar * LDAA + (2 * h + q) * 64 + ak] = pk;
      }
    }
  };

  // B loads: wave-private fragments of W[s_wind[gl]][co0+wn*32 .. +32][kk*64 .. +64]
  u16x8 breg[4];
  auto loadB = [&](int gl, int kkB) {
    const u16* wbn = wbf + (size_t)s_wind[gl] * (CI * CO)
                   + (size_t)(co0 + wn * 32) * CI + kkB;
#pragma unroll
    for (int rr = 0; rr < 4; ++rr) {
      int idx = lane + rr * 64, o = idx >> 3, ic = (idx & 7) * 8;
      breg[rr] = *(const u16x8*)(wbn + (size_t)o * CI + ic);
    }
  };

  loadB(0, 0);                               // prefetch B(0,0)
  const int T = ng * 4;

  for (int gl = 0; gl < ng; ++gl) {
    __syncthreads();                         // all waves done reading As (prev group)
    buildA(gl);
    __syncthreads();                         // As ready for all waves
    // 4 barrier-free MFMA phases: Bs is wave-private (producer == consumer),
    // so B prefetch loads stay in flight across phases (no vmcnt-draining barriers).
#pragma unroll
    for (int kk = 0; kk < 4; ++kk) {
      // stage this wave's B strip (compiler inserts counted vmcnt wait for breg)
#pragma unroll
      for (int rr = 0; rr < 4; ++rr) {
        int idx = lane + rr * 64, o = idx >> 3, ic = (idx & 7) * 8;
        *(u16x8*)&bsw[o * LDB + ic] = breg[rr];
      }
      // issue next-phase B loads (overlap this phase's MFMA)
      {
        int tn = gl * 4 + kk + 1; if (tn >= T) tn = T - 1;
        loadB(tn >> 2, (tn & 3) * BK);
      }
      // MFMA: ds_reads wait (lgkmcnt) on this wave's own strip writes only
#pragma unroll
      for (int ks = 0; ks < 2; ++ks) {
        short8 af[2], bfr[2];
#pragma unroll
        for (int mf = 0; mf < 2; ++mf)
          af[mf] = *(const short8*)&As[(mf * 16 + lrow) * LDAA + kk * 64 + ks * 32 + lq * 8];
#pragma unroll
        for (int nf = 0; nf < 2; ++nf)
          bfr[nf] = *(const short8*)&bsw[(nf * 16 + lrow) * LDB + ks * 32 + lq * 8];
#pragma unroll
        for (int mf = 0; mf < 2; ++mf)
#pragma unroll
          for (int nf = 0; nf < 2; ++nf)
            acc[mf][nf] = mfma_16x16x32_bf16(af[mf], bfr[nf], acc[mf][nf]);
      }
    }
  }

  // ---- epilogue: C layout col=lane&15, row=(lane>>4)*4+reg ----
#pragma unroll
  for (int mf = 0; mf < 2; ++mf) {
    int brow = b0 + mf * 16 + lq * 4;
#pragma unroll
    for (int nf = 0; nf < 2; ++nf) {
      int o = co0 + wn * 32 + nf * 16 + lrow;
#pragma unroll
      for (int rg = 0; rg < 4; ++rg)
        out[(size_t)(brow + rg) * (NO * CO) + (size_t)M * CO + o] = acc[mf][nf][rg];
    }
  }
}

extern "C" void kernel_launch(void* const* d_in, const int* in_sizes, int n_in,
                              void* d_out, int out_size, void* d_ws, size_t ws_size,
                              hipStream_t stream) {
  const float* x   = (const float*)d_in[0];
  const float* sh  = (const float*)d_in[1];
  const float* wgt = (const float*)d_in[2];
  const float* CG  = (const float*)d_in[3];
  const int* M1    = (const int*)d_in[4];
  const int* M2    = (const int*)d_in[5];
  const int* seg1  = (const int*)d_in[6];
  const int* lind  = (const int*)d_in[7];
  const int* seg2  = (const int*)d_in[8];
  float* out       = (float*)d_out;

  const int nnz = in_sizes[3];
  const int G   = in_sizes[7];
  const int n_w = in_sizes[2] / (CI * CO);

  u16* xbf = (u16*)d_ws;                                        // 8.39 MB
  u16* wbf = (u16*)((char*)d_ws + (size_t)B_SZ * NO * CI * 2);  // 4.46 MB

  int n8 = B_SZ * NO * CI / 8;
  xconv_kernel<<<dim3(n8 / 256), dim3(256), 0, stream>>>(x, xbf, n8);
  wconv_kernel<<<dim3(n_w * 16), dim3(256), 0, stream>>>(wgt, wbf);
  so3_main<<<dim3(1024), dim3(256), 0, stream>>>(xbf, sh, CG, wbf, M1, M2, seg1, lind, seg2,
                                                 out, G, nnz);
}